// Round 13
// baseline (32.197 us; speedup 1.0000x reference)
//
#include <hip/hip_runtime.h>

// MaxChamferDistance: x[16,4096,3], y[16,4096,3] f32 -> scalar f32
//
// Round-13: r12's mm (~24us) stalled on the serial per-tile min3 tree fed by
// MFMA latency (VALU model floor ~7.3us at 4 waves/SIMD). Change ONE thing:
// elementwise 16-wide running min (rm[nt] = min(rm[nt], acc)) -- 16
// INDEPENDENT v_min_f32 per MFMA, tree runs once in the epilogue instead of
// per tile. Same inst count, no serial chain. Everything else is r12 verbatim
// (2 launches, 64KB LDS one-shot A-staging, counter-fused combine, absmax 0).

typedef __attribute__((ext_vector_type(8)))  short bf16x8;
typedef __attribute__((ext_vector_type(16))) float f32x16;

#define BATCH   16
#define NPTS    4096
#define DB      (2 * BATCH)            // 32 (dir,batch)
#define GM_F32  (2 * DB * NPTS)        // 262144 f32 = 1 MB

static __device__ __forceinline__ unsigned bf16rn(float f) {
  unsigned u = __float_as_uint(f);
  return (u + 0x7FFFu + ((u >> 16) & 1u)) >> 16;   // round-to-nearest-even
}
static __device__ __forceinline__ float bf2f(unsigned h) {
  return __uint_as_float(h << 16);
}
static __device__ __forceinline__ unsigned pk(unsigned lo, unsigned hi) {
  return (lo & 0xFFFFu) | (hi << 16);
}

__global__ __launch_bounds__(512, 4) void chamfer_mm(
    const float* __restrict__ x, const float* __restrict__ y,
    float* __restrict__ gm, unsigned* __restrict__ cnt) {
  // 64 m-tiles x 64 uint4 (tile layout: [kh(2)][row(32)]) = 64 KB
  __shared__ __align__(16) uint4 afl[64 * 64];

  const int bid = blockIdx.x;          // 512 = 32 db x 8 own-chunks x 2 halves
  const int tid = threadIdx.x;
  if (bid == 0 && tid == 0) *cnt = 0;  // combine's counter (stream-ordered)

  const int db  = bid >> 4;
  const int r   = bid & 15;
  const int c   = r >> 1;              // own chunk [0,8)
  const int h   = r & 1;               // m-half
  const int dir = db >> 4, b = db & 15;
  const float* own   = (dir == 0 ? x : y) + (size_t)b * NPTS * 3;
  const float* other = (dir == 0 ? y : x) + (size_t)b * NPTS * 3;
  const float* mp    = other + (size_t)h * 2048 * 3;

  // ---- stage: convert 2048 other pts -> A-frags in LDS (4 pts/thread) ----
  #pragma unroll
  for (int k = 0; k < 4; ++k) {
    const int p = tid + k * 512;       // [0,2048)
    float y0 = mp[p * 3 + 0], y1 = mp[p * 3 + 1], y2 = mp[p * 3 + 2];
    float wv = fmaf(y2, y2, fmaf(y1, y1, y0 * y0));
    float z0 = -2.f * y0, z1 = -2.f * y1, z2 = -2.f * y2;
    unsigned h0 = bf16rn(z0), h1 = bf16rn(z1), h2 = bf16rn(z2);
    unsigned e0 = bf16rn(z0 - bf2f(h0));
    unsigned e1 = bf16rn(z1 - bf2f(h1));
    unsigned e2 = bf16rn(z2 - bf2f(h2));
    unsigned wh = bf16rn(wv), wl = bf16rn(wv - bf2f(wh));
    const int tile = p >> 5, row = p & 31;
    afl[tile * 64 + row]      =
        make_uint4(pk(h0, h1), pk(h2, e0), pk(e1, e2), pk(h0, h1)); // K0-7
    afl[tile * 64 + 32 + row] =
        make_uint4(pk(h2, wh), pk(wl, 0u), 0u, 0u);                 // K8-15
  }

  // ---- resident B-frags: 64 own pts per wave (2 n-tiles of 32) ----------
  const int w = tid >> 6, l = tid & 63;
  const int col = l & 31, kh = l >> 5;
  const unsigned ONE = 0x3F80u;
  bf16x8 bfr[2];
  float sq[2];
  #pragma unroll
  for (int nt = 0; nt < 2; ++nt) {
    const int n = c * 512 + w * 64 + nt * 32 + col;
    float a0 = own[n * 3 + 0], a1 = own[n * 3 + 1], a2 = own[n * 3 + 2];
    sq[nt] = fmaf(a2, a2, fmaf(a1, a1, a0 * a0));    // exact f32, added last
    unsigned h0 = bf16rn(a0), h1 = bf16rn(a1), h2 = bf16rn(a2);
    unsigned e0 = bf16rn(a0 - bf2f(h0));
    unsigned e1 = bf16rn(a1 - bf2f(h1));
    unsigned e2 = bf16rn(a2 - bf2f(h2));
    union { unsigned uu[4]; bf16x8 v; } U;
    U.uu[0] = (kh == 0) ? pk(h0, h1) : pk(e2, ONE);
    U.uu[1] = (kh == 0) ? pk(h2, h0) : pk(ONE, 0u);
    U.uu[2] = (kh == 0) ? pk(h1, h2) : 0u;
    U.uu[3] = (kh == 0) ? pk(e0, e1) : 0u;
    bfr[nt] = U.v;
  }
  __syncthreads();

  // ---- main loop: 16-wide elementwise running min (no serial tree) ------
  const int aoff = kh * 32 + col;      // lane's uint4 index within a tile
  const f32x16 z16 = {0.f, 0.f, 0.f, 0.f, 0.f, 0.f, 0.f, 0.f,
                      0.f, 0.f, 0.f, 0.f, 0.f, 0.f, 0.f, 0.f};
  f32x16 rm0 = {1e30f, 1e30f, 1e30f, 1e30f, 1e30f, 1e30f, 1e30f, 1e30f,
                1e30f, 1e30f, 1e30f, 1e30f, 1e30f, 1e30f, 1e30f, 1e30f};
  f32x16 rm1 = rm0;

  #pragma unroll 4
  for (int mt = 0; mt < 64; ++mt) {
    union { uint4 u; bf16x8 v; } A;
    A.u = afl[mt * 64 + aoff];
    f32x16 acc0 = __builtin_amdgcn_mfma_f32_32x32x16_bf16(
        A.v, bfr[0], z16, 0, 0, 0);
    f32x16 acc1 = __builtin_amdgcn_mfma_f32_32x32x16_bf16(
        A.v, bfr[1], z16, 0, 0, 0);
    rm0 = __builtin_elementwise_min(rm0, acc0);      // 16 independent v_min
    rm1 = __builtin_elementwise_min(rm1, acc1);
  }

  // ---- epilogue: tree once, fold lane^32, add exact ||x||^2, store ------
  #pragma unroll
  for (int nt = 0; nt < 2; ++nt) {
    const f32x16& rm = (nt == 0) ? rm0 : rm1;
    float m0 = fminf(fminf(rm[0],  rm[1]),  rm[2]);
    float m1 = fminf(fminf(rm[3],  rm[4]),  rm[5]);
    float m2 = fminf(fminf(rm[6],  rm[7]),  rm[8]);
    float m3 = fminf(fminf(rm[9],  rm[10]), rm[11]);
    float m4 = fminf(fminf(rm[12], rm[13]), rm[14]);
    float m5 = fminf(fminf(rm[15], m0), m1);
    float m6 = fminf(fminf(m2, m3), m4);
    float v  = fminf(m5, m6);
    v = fminf(v, __shfl_xor(v, 32, 64));
    float sv = v + sq[nt];
    if (l < 32)
      gm[(size_t)(h * DB + db) * NPTS + c * 512 + w * 64 + nt * 32 + col] = sv;
  }
}

// 32 blocks: min over halves + per-db mean; last block folds max/mean -> out.
__global__ __launch_bounds__(256) void chamfer_combine(
    const float* __restrict__ gm, float* __restrict__ dist,
    unsigned* __restrict__ cnt, float* __restrict__ out) {
  const int db = blockIdx.x;
  const float* g0 = gm + (size_t)db * NPTS;
  const float* g1 = gm + (size_t)(DB + db) * NPTS;
  float s = 0.0f;
  for (int i = threadIdx.x; i < NPTS; i += 256)
    s += fminf(g0[i], g1[i]);
  #pragma unroll
  for (int off = 32; off > 0; off >>= 1) s += __shfl_down(s, off, 64);
  __shared__ float red[4];
  const int lane = threadIdx.x & 63, wid = threadIdx.x >> 6;
  if (lane == 0) red[wid] = s;
  __syncthreads();
  if (threadIdx.x == 0) {
    dist[db] = ((red[0] + red[1]) + (red[2] + red[3])) * (1.0f / (float)NPTS);
    __threadfence();
    unsigned old = __hip_atomic_fetch_add(cnt, 1u, __ATOMIC_ACQ_REL,
                                          __HIP_MEMORY_SCOPE_AGENT);
    if (old == DB - 1) {
      __threadfence();
      float acc = 0.0f;
      #pragma unroll
      for (int b = 0; b < BATCH; ++b) {
        float d0 = __uint_as_float(__hip_atomic_load(
            (const unsigned*)&dist[b], __ATOMIC_RELAXED,
            __HIP_MEMORY_SCOPE_AGENT));
        float d1 = __uint_as_float(__hip_atomic_load(
            (const unsigned*)&dist[b + BATCH], __ATOMIC_RELAXED,
            __HIP_MEMORY_SCOPE_AGENT));
        acc += fmaxf(d0, d1);
      }
      out[0] = acc * (1.0f / (float)BATCH);
    }
  }
}

extern "C" void kernel_launch(void* const* d_in, const int* in_sizes, int n_in,
                              void* d_out, int out_size, void* d_ws, size_t ws_size,
                              hipStream_t stream) {
  const float* x = (const float*)d_in[0];
  const float* y = (const float*)d_in[1];
  float* out = (float*)d_out;

  float* gm     = (float*)d_ws;                    // 1 MB
  float* dist   = gm + GM_F32;                     // 32 f32
  unsigned* cnt = (unsigned*)(dist + DB);          // 1 u32

  chamfer_mm<<<512, 512, 0, stream>>>(x, y, gm, cnt);
  chamfer_combine<<<DB, 256, 0, stream>>>(gm, dist, cnt, out);
}

// Round 14
// 30.947 us; speedup vs baseline: 1.0404x; 1.0404x over previous
//
#include <hip/hip_runtime.h>

// MaxChamferDistance: x[16,4096,3], y[16,4096,3] f32 -> scalar f32
//
// Round-14: r12 (min3-tree, 64KB LDS, 4 waves/SIMD) = 29.8; r13 elementwise
// min regressed => inst count not the wall; MFMA-latency stalls at 4 w/SIMD
// are. ONE change vs r12: m-quarter tiles (1024 other pts, 32KB LDS) +
// 1024 blocks -> 3-4 blocks/CU = 6-8 waves/SIMD (launch_bounds(512,6),
// VGPR<=~85). Inner loop/numerics/combine verbatim from r12 (absmax 0).
//  - block = (db, own-chunk 512, m-quarter): stages 1024 other pts as
//    32x32x16 A-frags in 32KB LDS, 1 barrier, then 32 tiles x
//    [ds_read_b128 + 2 MFMA + min3 tree].
//  - gm[4][32][4096] (2MB) non-atomic; combine mins 4 quarters, counter-
//    fused finale (r9-proven). All fixed-order => replay-deterministic.

typedef __attribute__((ext_vector_type(8)))  short bf16x8;
typedef __attribute__((ext_vector_type(16))) float f32x16;

#define BATCH   16
#define NPTS    4096
#define DB      (2 * BATCH)            // 32 (dir,batch)
#define NQ      4                      // m-quarters
#define GM_F32  (NQ * DB * NPTS)       // 524288 f32 = 2 MB

static __device__ __forceinline__ unsigned bf16rn(float f) {
  unsigned u = __float_as_uint(f);
  return (u + 0x7FFFu + ((u >> 16) & 1u)) >> 16;   // round-to-nearest-even
}
static __device__ __forceinline__ float bf2f(unsigned h) {
  return __uint_as_float(h << 16);
}
static __device__ __forceinline__ unsigned pk(unsigned lo, unsigned hi) {
  return (lo & 0xFFFFu) | (hi << 16);
}

__global__ __launch_bounds__(512, 6) void chamfer_mm(
    const float* __restrict__ x, const float* __restrict__ y,
    float* __restrict__ gm, unsigned* __restrict__ cnt) {
  // 32 m-tiles x 64 uint4 (tile layout: [kh(2)][row(32)]) = 32 KB
  __shared__ __align__(16) uint4 afl[32 * 64];

  const int bid = blockIdx.x;          // 1024 = 32 db x 8 chunks x 4 quarters
  const int tid = threadIdx.x;
  if (bid == 0 && tid == 0) *cnt = 0;  // combine's counter (stream-ordered)

  const int db  = bid >> 5;
  const int r   = bid & 31;
  const int c   = r >> 2;              // own chunk [0,8)
  const int q   = r & 3;               // m-quarter
  const int dir = db >> 4, b = db & 15;
  const float* own   = (dir == 0 ? x : y) + (size_t)b * NPTS * 3;
  const float* other = (dir == 0 ? y : x) + (size_t)b * NPTS * 3;
  const float* mp    = other + (size_t)q * 1024 * 3;

  // ---- stage: convert 1024 other pts -> A-frags in LDS (2 pts/thread) ----
  #pragma unroll
  for (int k = 0; k < 2; ++k) {
    const int p = tid + k * 512;       // [0,1024)
    float y0 = mp[p * 3 + 0], y1 = mp[p * 3 + 1], y2 = mp[p * 3 + 2];
    float wv = fmaf(y2, y2, fmaf(y1, y1, y0 * y0));
    float z0 = -2.f * y0, z1 = -2.f * y1, z2 = -2.f * y2;
    unsigned h0 = bf16rn(z0), h1 = bf16rn(z1), h2 = bf16rn(z2);
    unsigned e0 = bf16rn(z0 - bf2f(h0));
    unsigned e1 = bf16rn(z1 - bf2f(h1));
    unsigned e2 = bf16rn(z2 - bf2f(h2));
    unsigned wh = bf16rn(wv), wl = bf16rn(wv - bf2f(wh));
    const int tile = p >> 5, row = p & 31;
    afl[tile * 64 + row]      =
        make_uint4(pk(h0, h1), pk(h2, e0), pk(e1, e2), pk(h0, h1)); // K0-7
    afl[tile * 64 + 32 + row] =
        make_uint4(pk(h2, wh), pk(wl, 0u), 0u, 0u);                 // K8-15
  }

  // ---- resident B-frags: 64 own pts per wave (2 n-tiles of 32) ----------
  const int w = tid >> 6, l = tid & 63;
  const int col = l & 31, kh = l >> 5;
  const unsigned ONE = 0x3F80u;
  bf16x8 bfr[2];
  float sq[2], rmn[2];
  #pragma unroll
  for (int nt = 0; nt < 2; ++nt) {
    const int n = c * 512 + w * 64 + nt * 32 + col;
    float a0 = own[n * 3 + 0], a1 = own[n * 3 + 1], a2 = own[n * 3 + 2];
    sq[nt]  = fmaf(a2, a2, fmaf(a1, a1, a0 * a0));   // exact f32, added last
    rmn[nt] = 1e30f;
    unsigned h0 = bf16rn(a0), h1 = bf16rn(a1), h2 = bf16rn(a2);
    unsigned e0 = bf16rn(a0 - bf2f(h0));
    unsigned e1 = bf16rn(a1 - bf2f(h1));
    unsigned e2 = bf16rn(a2 - bf2f(h2));
    union { unsigned uu[4]; bf16x8 v; } U;
    U.uu[0] = (kh == 0) ? pk(h0, h1) : pk(e2, ONE);
    U.uu[1] = (kh == 0) ? pk(h2, h0) : pk(ONE, 0u);
    U.uu[2] = (kh == 0) ? pk(h1, h2) : 0u;
    U.uu[3] = (kh == 0) ? pk(e0, e1) : 0u;
    bfr[nt] = U.v;
  }
  __syncthreads();

  // ---- main loop: 32 tiles x [1 ds_read_b128 + 2 MFMA + min3 tree] ------
  const int aoff = kh * 32 + col;      // lane's uint4 index within a tile
  const f32x16 z16 = {0.f, 0.f, 0.f, 0.f, 0.f, 0.f, 0.f, 0.f,
                      0.f, 0.f, 0.f, 0.f, 0.f, 0.f, 0.f, 0.f};
  #pragma unroll 2
  for (int mt = 0; mt < 32; ++mt) {
    union { uint4 u; bf16x8 v; } A;
    A.u = afl[mt * 64 + aoff];
    #pragma unroll
    for (int nt = 0; nt < 2; ++nt) {
      f32x16 acc = __builtin_amdgcn_mfma_f32_32x32x16_bf16(
          A.v, bfr[nt], z16, 0, 0, 0);
      float m0 = fminf(fminf(acc[0],  acc[1]),  acc[2]);   // v_min3 chains
      float m1 = fminf(fminf(acc[3],  acc[4]),  acc[5]);
      float m2 = fminf(fminf(acc[6],  acc[7]),  acc[8]);
      float m3 = fminf(fminf(acc[9],  acc[10]), acc[11]);
      float m4 = fminf(fminf(acc[12], acc[13]), acc[14]);
      float m5 = fminf(fminf(acc[15], m0), m1);
      float m6 = fminf(fminf(m2, m3), m4);
      rmn[nt] = fminf(fminf(m5, m6), rmn[nt]);
    }
  }

  // ---- epilogue: rows live in both lane halves -> fold lane^32 ----------
  #pragma unroll
  for (int nt = 0; nt < 2; ++nt) {
    float v = fminf(rmn[nt], __shfl_xor(rmn[nt], 32, 64));
    float sv = v + sq[nt];
    if (l < 32)
      gm[(size_t)(q * DB + db) * NPTS + c * 512 + w * 64 + nt * 32 + col] = sv;
  }
}

// 32 blocks: min over quarters + per-db mean; last block folds max/mean.
__global__ __launch_bounds__(256) void chamfer_combine(
    const float* __restrict__ gm, float* __restrict__ dist,
    unsigned* __restrict__ cnt, float* __restrict__ out) {
  const int db = blockIdx.x;
  float s = 0.0f;
  for (int i = threadIdx.x; i < NPTS; i += 256) {
    const size_t o = (size_t)db * NPTS + i;
    float v0 = gm[o];
    float v1 = gm[o + (size_t)DB * NPTS];
    float v2 = gm[o + (size_t)2 * DB * NPTS];
    float v3 = gm[o + (size_t)3 * DB * NPTS];
    s += fminf(fminf(v0, v1), fminf(v2, v3));
  }
  #pragma unroll
  for (int off = 32; off > 0; off >>= 1) s += __shfl_down(s, off, 64);
  __shared__ float red[4];
  const int lane = threadIdx.x & 63, wid = threadIdx.x >> 6;
  if (lane == 0) red[wid] = s;
  __syncthreads();
  if (threadIdx.x == 0) {
    dist[db] = ((red[0] + red[1]) + (red[2] + red[3])) * (1.0f / (float)NPTS);
    __threadfence();
    unsigned old = __hip_atomic_fetch_add(cnt, 1u, __ATOMIC_ACQ_REL,
                                          __HIP_MEMORY_SCOPE_AGENT);
    if (old == DB - 1) {
      __threadfence();
      float acc = 0.0f;
      #pragma unroll
      for (int b = 0; b < BATCH; ++b) {
        float d0 = __uint_as_float(__hip_atomic_load(
            (const unsigned*)&dist[b], __ATOMIC_RELAXED,
            __HIP_MEMORY_SCOPE_AGENT));
        float d1 = __uint_as_float(__hip_atomic_load(
            (const unsigned*)&dist[b + BATCH], __ATOMIC_RELAXED,
            __HIP_MEMORY_SCOPE_AGENT));
        acc += fmaxf(d0, d1);
      }
      out[0] = acc * (1.0f / (float)BATCH);
    }
  }
}

extern "C" void kernel_launch(void* const* d_in, const int* in_sizes, int n_in,
                              void* d_out, int out_size, void* d_ws, size_t ws_size,
                              hipStream_t stream) {
  const float* x = (const float*)d_in[0];
  const float* y = (const float*)d_in[1];
  float* out = (float*)d_out;

  float* gm     = (float*)d_ws;                    // 2 MB
  float* dist   = gm + GM_F32;                     // 32 f32
  unsigned* cnt = (unsigned*)(dist + DB);          // 1 u32

  chamfer_mm<<<1024, 512, 0, stream>>>(x, y, gm, cnt);
  chamfer_combine<<<DB, 256, 0, stream>>>(gm, dist, cnt, out);
}

// Round 15
// 30.851 us; speedup vs baseline: 1.0436x; 1.0031x over previous
//
#include <hip/hip_runtime.h>

// MaxChamferDistance: x[16,4096,3], y[16,4096,3] f32 -> scalar f32
//
// Round-15: mm pinned ~24us across occupancy (r12/r14), min structure (r13).
// Remaining untested mechanism: in-wave ILP. NT=4 resident B-frags => 4
// INDEPENDENT MFMA+min chains per A-tile read (DS/MFMA halved, MFMA issue
// back-to-back like the 2495TF ubench pattern).
//  - TPB=256 (4 waves), block = (db, own-chunk 512, m-quarter 1024):
//    grid = 32x8x4 = 1024 blocks = 4 blocks/CU (LDS 32KB x4 = 128 <= 160).
//  - per wave: 32 tiles x [1 ds_read_b128 + 4 MFMA 32x32x16 + 32 min3].
//  - numerics/layouts r12-verbatim (absmax 0 x5): A=[ybh(3),ybl(3),ybh(3),
//    wh,wl], B=[xh(3),xh(3),xl(3),1,1]; exact-f32 ||x||^2 post-min.
//  - gm[4][32][4096] (2MB) non-atomic; combine mins 4 quarters; counter-
//    fused finale (proven). All fixed-order => replay-deterministic.

typedef __attribute__((ext_vector_type(8)))  short bf16x8;
typedef __attribute__((ext_vector_type(16))) float f32x16;

#define BATCH   16
#define NPTS    4096
#define DB      (2 * BATCH)            // 32 (dir,batch)
#define NQ      4                      // m-quarters
#define NT      4                      // resident B-frags per wave
#define GM_F32  (NQ * DB * NPTS)       // 524288 f32 = 2 MB

static __device__ __forceinline__ unsigned bf16rn(float f) {
  unsigned u = __float_as_uint(f);
  return (u + 0x7FFFu + ((u >> 16) & 1u)) >> 16;   // round-to-nearest-even
}
static __device__ __forceinline__ float bf2f(unsigned h) {
  return __uint_as_float(h << 16);
}
static __device__ __forceinline__ unsigned pk(unsigned lo, unsigned hi) {
  return (lo & 0xFFFFu) | (hi << 16);
}

__global__ __launch_bounds__(256, 4) void chamfer_mm(
    const float* __restrict__ x, const float* __restrict__ y,
    float* __restrict__ gm, unsigned* __restrict__ cnt) {
  // 32 m-tiles x 64 uint4 (tile layout: [kh(2)][row(32)]) = 32 KB
  __shared__ __align__(16) uint4 afl[32 * 64];

  const int bid = blockIdx.x;          // 1024 = 32 db x 8 chunks x 4 quarters
  const int tid = threadIdx.x;
  if (bid == 0 && tid == 0) *cnt = 0;  // combine's counter (stream-ordered)

  const int db  = bid >> 5;
  const int r   = bid & 31;
  const int c   = r >> 2;              // own chunk   [0,8)
  const int q   = r & 3;               // m-quarter   [0,4)
  const int dir = db >> 4, b = db & 15;
  const float* own   = (dir == 0 ? x : y) + (size_t)b * NPTS * 3;
  const float* other = (dir == 0 ? y : x) + (size_t)b * NPTS * 3;
  const float* mp    = other + (size_t)q * 1024 * 3;

  // ---- stage: convert 1024 other pts -> A-frags in LDS (4 pts/thread) ----
  #pragma unroll
  for (int k = 0; k < 4; ++k) {
    const int p = tid + k * 256;       // [0,1024)
    float y0 = mp[p * 3 + 0], y1 = mp[p * 3 + 1], y2 = mp[p * 3 + 2];
    float wv = fmaf(y2, y2, fmaf(y1, y1, y0 * y0));
    float z0 = -2.f * y0, z1 = -2.f * y1, z2 = -2.f * y2;
    unsigned h0 = bf16rn(z0), h1 = bf16rn(z1), h2 = bf16rn(z2);
    unsigned e0 = bf16rn(z0 - bf2f(h0));
    unsigned e1 = bf16rn(z1 - bf2f(h1));
    unsigned e2 = bf16rn(z2 - bf2f(h2));
    unsigned wh = bf16rn(wv), wl = bf16rn(wv - bf2f(wh));
    const int tile = p >> 5, row = p & 31;
    afl[tile * 64 + row]      =
        make_uint4(pk(h0, h1), pk(h2, e0), pk(e1, e2), pk(h0, h1)); // K0-7
    afl[tile * 64 + 32 + row] =
        make_uint4(pk(h2, wh), pk(wl, 0u), 0u, 0u);                 // K8-15
  }

  // ---- resident B-frags: 128 own pts per wave (4 n-tiles of 32) ----------
  const int w = tid >> 6, l = tid & 63;
  const int col = l & 31, kh = l >> 5;
  const unsigned ONE = 0x3F80u;
  bf16x8 bfr[NT];
  float sq[NT], rmn[NT];
  #pragma unroll
  for (int nt = 0; nt < NT; ++nt) {
    const int n = c * 512 + w * 128 + nt * 32 + col;
    float a0 = own[n * 3 + 0], a1 = own[n * 3 + 1], a2 = own[n * 3 + 2];
    sq[nt]  = fmaf(a2, a2, fmaf(a1, a1, a0 * a0));   // exact f32, added last
    rmn[nt] = 1e30f;
    unsigned h0 = bf16rn(a0), h1 = bf16rn(a1), h2 = bf16rn(a2);
    unsigned e0 = bf16rn(a0 - bf2f(h0));
    unsigned e1 = bf16rn(a1 - bf2f(h1));
    unsigned e2 = bf16rn(a2 - bf2f(h2));
    union { unsigned uu[4]; bf16x8 v; } U;
    U.uu[0] = (kh == 0) ? pk(h0, h1) : pk(e2, ONE);
    U.uu[1] = (kh == 0) ? pk(h2, h0) : pk(ONE, 0u);
    U.uu[2] = (kh == 0) ? pk(h1, h2) : 0u;
    U.uu[3] = (kh == 0) ? pk(e0, e1) : 0u;
    bfr[nt] = U.v;
  }
  __syncthreads();

  // ---- main loop: 32 tiles x [1 ds_read_b128 + 4 indep MFMA + min3] -----
  const int aoff = kh * 32 + col;      // lane's uint4 index within a tile
  const f32x16 z16 = {0.f, 0.f, 0.f, 0.f, 0.f, 0.f, 0.f, 0.f,
                      0.f, 0.f, 0.f, 0.f, 0.f, 0.f, 0.f, 0.f};
  #pragma unroll 2
  for (int mt = 0; mt < 32; ++mt) {
    union { uint4 u; bf16x8 v; } A;
    A.u = afl[mt * 64 + aoff];
    #pragma unroll
    for (int nt = 0; nt < NT; ++nt) {
      f32x16 acc = __builtin_amdgcn_mfma_f32_32x32x16_bf16(
          A.v, bfr[nt], z16, 0, 0, 0);
      float m0 = fminf(fminf(acc[0],  acc[1]),  acc[2]);   // v_min3 chains
      float m1 = fminf(fminf(acc[3],  acc[4]),  acc[5]);
      float m2 = fminf(fminf(acc[6],  acc[7]),  acc[8]);
      float m3 = fminf(fminf(acc[9],  acc[10]), acc[11]);
      float m4 = fminf(fminf(acc[12], acc[13]), acc[14]);
      float m5 = fminf(fminf(acc[15], m0), m1);
      float m6 = fminf(fminf(m2, m3), m4);
      rmn[nt] = fminf(fminf(m5, m6), rmn[nt]);
    }
  }

  // ---- epilogue: rows live in both lane halves -> fold lane^32 ----------
  #pragma unroll
  for (int nt = 0; nt < NT; ++nt) {
    float v = fminf(rmn[nt], __shfl_xor(rmn[nt], 32, 64));
    float sv = v + sq[nt];
    if (l < 32)
      gm[(size_t)(q * DB + db) * NPTS + c * 512 + w * 128 + nt * 32 + col]
          = sv;
  }
}

// 32 blocks: min over quarters + per-db mean; last block folds max/mean.
__global__ __launch_bounds__(256) void chamfer_combine(
    const float* __restrict__ gm, float* __restrict__ dist,
    unsigned* __restrict__ cnt, float* __restrict__ out) {
  const int db = blockIdx.x;
  float s = 0.0f;
  for (int i = threadIdx.x; i < NPTS; i += 256) {
    const size_t o = (size_t)db * NPTS + i;
    float v0 = gm[o];
    float v1 = gm[o + (size_t)DB * NPTS];
    float v2 = gm[o + (size_t)2 * DB * NPTS];
    float v3 = gm[o + (size_t)3 * DB * NPTS];
    s += fminf(fminf(v0, v1), fminf(v2, v3));
  }
  #pragma unroll
  for (int off = 32; off > 0; off >>= 1) s += __shfl_down(s, off, 64);
  __shared__ float red[4];
  const int lane = threadIdx.x & 63, wid = threadIdx.x >> 6;
  if (lane == 0) red[wid] = s;
  __syncthreads();
  if (threadIdx.x == 0) {
    dist[db] = ((red[0] + red[1]) + (red[2] + red[3])) * (1.0f / (float)NPTS);
    __threadfence();
    unsigned old = __hip_atomic_fetch_add(cnt, 1u, __ATOMIC_ACQ_REL,
                                          __HIP_MEMORY_SCOPE_AGENT);
    if (old == DB - 1) {
      __threadfence();
      float acc = 0.0f;
      #pragma unroll
      for (int b = 0; b < BATCH; ++b) {
        float d0 = __uint_as_float(__hip_atomic_load(
            (const unsigned*)&dist[b], __ATOMIC_RELAXED,
            __HIP_MEMORY_SCOPE_AGENT));
        float d1 = __uint_as_float(__hip_atomic_load(
            (const unsigned*)&dist[b + BATCH], __ATOMIC_RELAXED,
            __HIP_MEMORY_SCOPE_AGENT));
        acc += fmaxf(d0, d1);
      }
      out[0] = acc * (1.0f / (float)BATCH);
    }
  }
}

extern "C" void kernel_launch(void* const* d_in, const int* in_sizes, int n_in,
                              void* d_out, int out_size, void* d_ws, size_t ws_size,
                              hipStream_t stream) {
  const float* x = (const float*)d_in[0];
  const float* y = (const float*)d_in[1];
  float* out = (float*)d_out;

  float* gm     = (float*)d_ws;                    // 2 MB
  float* dist   = gm + GM_F32;                     // 32 f32
  unsigned* cnt = (unsigned*)(dist + DB);          // 1 u32

  chamfer_mm<<<1024, 256, 0, stream>>>(x, y, gm, cnt);
  chamfer_combine<<<DB, 256, 0, stream>>>(gm, dist, cnt, out);
}